// Round 7
// baseline (2223.112 us; speedup 1.0000x reference)
//
#include <hip/hip_runtime.h>
#include <math.h>

#define BD 16384            // B*D
#define TT 512
#define KDIM 1024
#define NDIM 1024
#define GEMM_M 8192
#define PANEL_Q 320         // OpenBLAS SGEMM_DEFAULT_Q (SKYLAKEX/COOPERLAKE AVX512 path)

// ===========================================================================
// Scan transcendentals: ROCm native f32 libm (kept identical to r6 so the
// GEMM realization is the only changed variable this round).
// Compound arithmetic uses __fadd_rn/__fmul_rn/__fsub_rn to forbid FMA
// contraction (the np reference is mul/add at f32).
// ===========================================================================
__device__ __forceinline__ float np_expf(float x)   { return expf(x); }
__device__ __forceinline__ float np_logf(float x)   { return logf(x); }
__device__ __forceinline__ float np_log1pf(float x) { return log1pf(x); }

// npy_logaddexpf(v, 0) — exact structure of numpy's scalar logaddexp loop;
// this is what jax.nn.softplus / log_sigmoid transpile to.
__device__ __forceinline__ float np_softplus(float v) {
    if (v == 0.0f) return 0.69314718246459960938f;   // x==y: x + NPY_LOGE2f
    if (v > 0.0f)  return __fadd_rn(v, np_log1pf(np_expf(-v)));
    return np_log1pf(np_expf(v));                     // y(=0) + log1p(exp(tmp))
}

__device__ __forceinline__ void np_sla(float la, float sa, float lb, float sb,
                                       float& lo, float& so) {
    bool az = la <= -39.0f;                  // LOG_ZERO + 1
    bool bz = lb <= -39.0f;
    float mx = fmaxf(la, lb);
    float mn = fminf(la, lb);
    float diff = __fsub_rn(mn, mx);
    bool amax = la >= lb;
    float smax = amax ? sa : sb;
    float smin = amax ? sb : sa;
    bool same = __fmul_rn(smax, smin) > 0.0f;
    float ed = np_expf(diff);                          // np.exp (array op)
    float ls  = __fadd_rn(mx, np_log1pf(ed));          // np.log1p (array op)
    float lop = __fadd_rn(mx, np_log1pf(-fminf(ed, 0.9999f)));
    float l = same ? ls : lop;
    float s = smax;
    l = az ? lb : l;  s = az ? sb : s;
    bool bo = bz && !az;
    l = bo ? la : l;  s = bo ? sa : s;
    lo = l; so = s;
}

__device__ __forceinline__ void np_step(float araw, float lin, float draw,
                                        float lrh, float srh,
                                        float& lhp, float& shp,
                                        float* o_log, float* o_sign, float* o_h) {
    const float alpha = __fadd_rn(1.0f, np_softplus(araw));
    const float ax = fabsf(lin);
    const float log_in = (ax > 1e-10f) ? np_logf(fmaxf(ax, 1e-10f)) : -40.0f;
    const float sign_in = (lin < 0.0f) ? -1.0f : 1.0f;   // np.sign, 0 -> 1
    const float log_d   = -np_softplus(-draw);           // log_sigmoid(draw)
    const float log_1md = -np_softplus(draw);            // log_sigmoid(-draw)

    const float log_rh  = __fadd_rn(lrh, lhp);
    const float sign_rh = __fmul_rn(srh, shp);
    float lv, sv;
    np_sla(log_rh, sign_rh, log_in, sign_in, lv, sv);
    const float tt = __fmul_rn(alpha, lv);
    const float log_cand = -np_softplus(-tt);            // soft_bound_log
    float lhn, shn;
    np_sla(__fadd_rn(log_1md, lhp), shp, __fadd_rn(log_d, log_cand), sv, lhn, shn);

    const float res = __fmul_rn(shn, np_expf(fminf(lhn, 20.0f)));
    const float h = (lhn > -39.0f) ? res : 0.0f;
    *o_log = lhn; *o_sign = shn; *o_h = h;
    lhp = lhn; shp = shn;
}

// ===========================================================================
// OpenBLAS-sgemm-exact NT-GEMM (np.einsum optimize=True -> tensordot ->
// np.dot -> cblas_sgemm; AVX512 SKYLAKEX/COOPERLAKE path):
//   per output element: single-accumulator FMA chain, k strictly ascending,
//   split at K-panel boundaries Q=320 -> panels {320,320,320,64};
//   partials folded left-assoc into C: (((p1+p2)+p3)+p4);
//   bias added afterwards by numpy as one separate f32 add.
// GPU __fmaf_rn == x86 vfmadd bit-exactly; tiling only reorders memory.
// Tile 64x64, BK=16, 256 threads, 4x4 outputs/thread.
// ===========================================================================
__global__ __launch_bounds__(256) void gemm_blas(
    const float* __restrict__ x,
    const float* __restrict__ Wa, const float* __restrict__ Wx, const float* __restrict__ Wd,
    const float* __restrict__ ba, const float* __restrict__ bx, const float* __restrict__ bd,
    float* __restrict__ out_a, float* __restrict__ out_x, float* __restrict__ out_d)
{
    const int z = blockIdx.z;
    const float* W    = (z == 0) ? Wa : (z == 1) ? Wx : Wd;
    const float* bias = (z == 0) ? ba : (z == 1) ? bx : bd;
    float* out        = (z == 0) ? out_a : (z == 1) ? out_x : out_d;

    const int m0 = blockIdx.x * 64;
    const int n0 = blockIdx.y * 64;

    __shared__ float As[16][68];   // [k in tile][m]
    __shared__ float Bs[16][68];   // [k in tile][n]

    const int tid = threadIdx.x;
    const int lr = tid >> 2;       // 0..63 staging row
    const int lc = tid & 3;        // float4 column
    const int ty = tid >> 4;       // 0..15 -> m = ty*4 + i
    const int tx = tid & 15;       // 0..15 -> n = tx*4 + j

    const float* Ap = x + (size_t)(m0 + lr) * KDIM + lc * 4;
    const float* Bp = W + (size_t)(n0 + lr) * KDIM + lc * 4;

    float4 fa = *(const float4*)Ap;
    float4 fb = *(const float4*)Bp;

    float tot[4][4];               // folded finished panels
    float acc[4][4];               // current panel FMA chain
    #pragma unroll
    for (int i = 0; i < 4; ++i)
        #pragma unroll
        for (int j = 0; j < 4; ++j) { tot[i][j] = 0.0f; acc[i][j] = 0.0f; }

    for (int kt = 0; kt < KDIM; kt += 16) {
        if (kt == PANEL_Q || kt == 2 * PANEL_Q || kt == 3 * PANEL_Q) {
            #pragma unroll
            for (int i = 0; i < 4; ++i)
                #pragma unroll
                for (int j = 0; j < 4; ++j) {
                    tot[i][j] = __fadd_rn(tot[i][j], acc[i][j]);  // C += panel
                    acc[i][j] = 0.0f;
                }
        }
        __syncthreads();
        {
            const float* pa = (const float*)&fa;
            const float* pb = (const float*)&fb;
            #pragma unroll
            for (int c = 0; c < 4; ++c) {
                As[lc * 4 + c][lr] = pa[c];
                Bs[lc * 4 + c][lr] = pb[c];
            }
        }
        __syncthreads();
        if (kt + 16 < KDIM) {
            fa = *(const float4*)(Ap + kt + 16);
            fb = *(const float4*)(Bp + kt + 16);
        }
        #pragma unroll
        for (int kk = 0; kk < 16; ++kk) {          // k strictly ascending
            const float4 a = *(const float4*)&As[kk][ty * 4];
            const float4 b = *(const float4*)&Bs[kk][tx * 4];
            const float av[4] = {a.x, a.y, a.z, a.w};
            const float bv[4] = {b.x, b.y, b.z, b.w};
            #pragma unroll
            for (int i = 0; i < 4; ++i)
                #pragma unroll
                for (int j = 0; j < 4; ++j)
                    acc[i][j] = __fmaf_rn(av[i], bv[j], acc[i][j]);
        }
    }
    #pragma unroll
    for (int i = 0; i < 4; ++i)                    // fold last (64-wide) panel
        #pragma unroll
        for (int j = 0; j < 4; ++j)
            tot[i][j] = __fadd_rn(tot[i][j], acc[i][j]);

    float bj[4];
    #pragma unroll
    for (int j = 0; j < 4; ++j) bj[j] = bias[n0 + tx * 4 + j];

    #pragma unroll
    for (int i = 0; i < 4; ++i) {
        float4 v;
        float* op = out + (size_t)(m0 + ty * 4 + i) * NDIM + n0 + tx * 4;
        v.x = __fadd_rn(tot[i][0], bj[0]);
        v.y = __fadd_rn(tot[i][1], bj[1]);
        v.z = __fadd_rn(tot[i][2], bj[2]);
        v.w = __fadd_rn(tot[i][3], bj[3]);
        *(float4*)op = v;
    }
}

// ===========================================================================
// f32 scan, T=512, one thread per (b,d). Inputs alias d_out (alpha_raw ->
// h_lin rows, lin -> log_h rows 1.., delta_raw -> sign_h rows 1..), written
// back in place by the same thread after use. Depth-4 register prefetch.
// ===========================================================================
__global__ __launch_bounds__(64) void scan_kernel(
    float* __restrict__ log_h, float* __restrict__ sign_h, float* __restrict__ h_lin,
    const float* __restrict__ log_r_h, const float* __restrict__ sign_r_h)
{
    const int idx = blockIdx.x * 64 + threadIdx.x;
    const int d = idx & 1023;
    const float lrh = log_r_h[d];
    const float srh = sign_r_h[d];

    log_h[idx] = -40.0f;
    sign_h[idx] = 1.0f;

    float lhp = -40.0f;
    float shp = 1.0f;

    float pa[4], pl[4], pd[4];
    #pragma unroll
    for (int u = 0; u < 4; ++u) {
        pa[u] = h_lin[(size_t)u * BD + idx];
        pl[u] = log_h[(size_t)(u + 1) * BD + idx];
        pd[u] = sign_h[(size_t)(u + 1) * BD + idx];
    }

    for (int t4 = 0; t4 < TT; t4 += 4) {
        #pragma unroll
        for (int u = 0; u < 4; ++u) {
            const int t = t4 + u;
            const float araw = pa[u];
            const float lin  = pl[u];
            const float draw = pd[u];
            const int tn = t + 4;
            if (tn < TT) {
                pa[u] = h_lin[(size_t)tn * BD + idx];
                pl[u] = log_h[(size_t)(tn + 1) * BD + idx];
                pd[u] = sign_h[(size_t)(tn + 1) * BD + idx];
            }
            np_step(araw, lin, draw, lrh, srh, lhp, shp,
                    &log_h[(size_t)(t + 1) * BD + idx],
                    &sign_h[(size_t)(t + 1) * BD + idx],
                    &h_lin[(size_t)t * BD + idx]);
        }
    }
}

// ===========================================================================
extern "C" void kernel_launch(void* const* d_in, const int* in_sizes, int n_in,
                              void* d_out, int out_size, void* d_ws, size_t ws_size,
                              hipStream_t stream) {
    const float* x        = (const float*)d_in[0];
    const float* W_x      = (const float*)d_in[1];
    const float* W_alpha  = (const float*)d_in[2];
    const float* W_delta  = (const float*)d_in[3];
    const float* b        = (const float*)d_in[4];
    const float* b_alpha  = (const float*)d_in[5];
    const float* b_delta  = (const float*)d_in[6];
    const float* log_r_h  = (const float*)d_in[7];
    const float* sign_r_h = (const float*)d_in[8];

    float* out    = (float*)d_out;
    float* log_h  = out;                            // [513, BD]
    float* sign_h = out + (size_t)513 * BD;         // [513, BD]
    float* h_lin  = out + (size_t)2 * 513 * BD;     // [512, BD]

    dim3 ggrid(GEMM_M / 64, NDIM / 64, 3);
    gemm_blas<<<ggrid, dim3(256), 0, stream>>>(
        x, W_alpha, W_x, W_delta, b_alpha, b, b_delta,
        h_lin, log_h + BD, sign_h + BD);

    scan_kernel<<<dim3(BD / 64), dim3(64), 0, stream>>>(
        log_h, sign_h, h_lin, log_r_h, sign_r_h);
}

// Round 8
// 1922.804 us; speedup vs baseline: 1.1562x; 1.1562x over previous
//
#include <hip/hip_runtime.h>
#include <math.h>

#define BD 16384            // B*D
#define TT 512
#define KDIM 1024
#define NDIM 1024
#define GEMM_M 8192
#define PANEL_Q 320         // OpenBLAS SGEMM_DEFAULT_Q (SKYLAKEX/COOPERLAKE AVX512 path)

// ===========================================================================
// Scan transcendentals: ROCm native f32 libm — FROZEN (r7 passed with these).
// Compound arithmetic uses __fadd_rn/__fmul_rn/__fsub_rn to forbid FMA
// contraction. Every formula below is op-for-op identical to r7.
// ===========================================================================
__device__ __forceinline__ float np_expf(float x)   { return expf(x); }
__device__ __forceinline__ float np_logf(float x)   { return logf(x); }
__device__ __forceinline__ float np_log1pf(float x) { return log1pf(x); }

// npy_logaddexpf(v, 0) — numpy scalar logaddexp structure (r7-identical).
__device__ __forceinline__ float np_softplus(float v) {
    if (v == 0.0f) return 0.69314718246459960938f;   // x==y: x + NPY_LOGE2f
    if (v > 0.0f)  return __fadd_rn(v, np_log1pf(np_expf(-v)));
    return np_log1pf(np_expf(v));                     // y(=0) + log1p(exp(tmp))
}

__device__ __forceinline__ void np_sla(float la, float sa, float lb, float sb,
                                       float& lo, float& so) {
    bool az = la <= -39.0f;                  // LOG_ZERO + 1
    bool bz = lb <= -39.0f;
    float mx = fmaxf(la, lb);
    float mn = fminf(la, lb);
    float diff = __fsub_rn(mn, mx);
    bool amax = la >= lb;
    float smax = amax ? sa : sb;
    float smin = amax ? sb : sa;
    bool same = __fmul_rn(smax, smin) > 0.0f;
    float ed = np_expf(diff);
    float ls  = __fadd_rn(mx, np_log1pf(ed));
    float lop = __fadd_rn(mx, np_log1pf(-fminf(ed, 0.9999f)));
    float l = same ? ls : lop;
    float s = smax;
    l = az ? lb : l;  s = az ? sb : s;
    bool bo = bz && !az;
    l = bo ? la : l;  s = bo ? sa : s;
    lo = l; so = s;
}

// ---------------------------------------------------------------------------
// Input transform (off the serial critical path; depends only on GEMM
// outputs). Bit-identical to r7's in-step computation:
//  - alpha   = 1 + np_softplus(araw)
//  - log_in  = logf(max(|lin|,1e-10)) or -40 ;  sign_in = sign(lin), 0->+1
//  - log_d   = -np_softplus(-draw), log_1md = -np_softplus(draw)
//    shared per numpy's own branch structure:
//      draw>0: softplus(-draw)=log1p(exp(-draw)) = l1 ; softplus(draw)=draw+l1
//      draw<0: softplus(-draw)=-draw+l1          ; softplus(draw)=l1
//      draw=0: both = NPY_LOGE2f
//    with e = expf(-|draw|), l1 = log1pf(e)  (identical call args to r7).
// ---------------------------------------------------------------------------
__device__ __forceinline__ void xform(float araw, float lin, float draw,
                                      float& alpha, float& log_in, float& sign_in,
                                      float& log_d, float& log_1md) {
    alpha = __fadd_rn(1.0f, np_softplus(araw));
    const float ax = fabsf(lin);
    log_in  = (ax > 1e-10f) ? np_logf(fmaxf(ax, 1e-10f)) : -40.0f;
    sign_in = (lin < 0.0f) ? -1.0f : 1.0f;
    if (draw == 0.0f) {
        log_d   = -0.69314718246459960938f;
        log_1md = -0.69314718246459960938f;
    } else {
        const float e  = np_expf(-fabsf(draw));
        const float l1 = np_log1pf(e);
        const float big = -__fadd_rn(fabsf(draw), l1);   // -(|draw| + l1)
        const float sml = -l1;
        log_d   = (draw > 0.0f) ? sml : big;
        log_1md = (draw > 0.0f) ? big : sml;
    }
}

// Serial recurrence section only (consumes pre-transformed values).
__device__ __forceinline__ void serial_step(float alpha, float log_in, float sign_in,
                                            float log_d, float log_1md,
                                            float lrh, float srh,
                                            float& lhp, float& shp,
                                            float* o_log, float* o_sign, float* o_h) {
    const float log_rh  = __fadd_rn(lrh, lhp);
    const float sign_rh = __fmul_rn(srh, shp);
    float lv, sv;
    np_sla(log_rh, sign_rh, log_in, sign_in, lv, sv);
    const float tt = __fmul_rn(alpha, lv);
    const float log_cand = -np_softplus(-tt);            // soft_bound_log
    float lhn, shn;
    np_sla(__fadd_rn(log_1md, lhp), shp, __fadd_rn(log_d, log_cand), sv, lhn, shn);

    const float res = __fmul_rn(shn, np_expf(fminf(lhn, 20.0f)));
    const float h = (lhn > -39.0f) ? res : 0.0f;
    *o_log = lhn; *o_sign = shn; *o_h = h;
    lhp = lhn; shp = shn;
}

// ===========================================================================
// OpenBLAS-sgemm-exact NT-GEMM — FROZEN (r7 passed): single-accumulator FMA
// chain, k ascending, Q=320 panels {320,320,320,64}, left-assoc fold, bias as
// separate f32 add. Tile 64x64, BK=16, 256 threads, 4x4 outputs/thread.
// ===========================================================================
__global__ __launch_bounds__(256) void gemm_blas(
    const float* __restrict__ x,
    const float* __restrict__ Wa, const float* __restrict__ Wx, const float* __restrict__ Wd,
    const float* __restrict__ ba, const float* __restrict__ bx, const float* __restrict__ bd,
    float* __restrict__ out_a, float* __restrict__ out_x, float* __restrict__ out_d)
{
    const int z = blockIdx.z;
    const float* W    = (z == 0) ? Wa : (z == 1) ? Wx : Wd;
    const float* bias = (z == 0) ? ba : (z == 1) ? bx : bd;
    float* out        = (z == 0) ? out_a : (z == 1) ? out_x : out_d;

    const int m0 = blockIdx.x * 64;
    const int n0 = blockIdx.y * 64;

    __shared__ float As[16][68];   // [k in tile][m]
    __shared__ float Bs[16][68];   // [k in tile][n]

    const int tid = threadIdx.x;
    const int lr = tid >> 2;       // 0..63 staging row
    const int lc = tid & 3;        // float4 column
    const int ty = tid >> 4;       // 0..15 -> m = ty*4 + i
    const int tx = tid & 15;       // 0..15 -> n = tx*4 + j

    const float* Ap = x + (size_t)(m0 + lr) * KDIM + lc * 4;
    const float* Bp = W + (size_t)(n0 + lr) * KDIM + lc * 4;

    float4 fa = *(const float4*)Ap;
    float4 fb = *(const float4*)Bp;

    float tot[4][4];               // folded finished panels
    float acc[4][4];               // current panel FMA chain
    #pragma unroll
    for (int i = 0; i < 4; ++i)
        #pragma unroll
        for (int j = 0; j < 4; ++j) { tot[i][j] = 0.0f; acc[i][j] = 0.0f; }

    for (int kt = 0; kt < KDIM; kt += 16) {
        if (kt == PANEL_Q || kt == 2 * PANEL_Q || kt == 3 * PANEL_Q) {
            #pragma unroll
            for (int i = 0; i < 4; ++i)
                #pragma unroll
                for (int j = 0; j < 4; ++j) {
                    tot[i][j] = __fadd_rn(tot[i][j], acc[i][j]);  // C += panel
                    acc[i][j] = 0.0f;
                }
        }
        __syncthreads();
        {
            const float* pa = (const float*)&fa;
            const float* pb = (const float*)&fb;
            #pragma unroll
            for (int c = 0; c < 4; ++c) {
                As[lc * 4 + c][lr] = pa[c];
                Bs[lc * 4 + c][lr] = pb[c];
            }
        }
        __syncthreads();
        if (kt + 16 < KDIM) {
            fa = *(const float4*)(Ap + kt + 16);
            fb = *(const float4*)(Bp + kt + 16);
        }
        #pragma unroll
        for (int kk = 0; kk < 16; ++kk) {          // k strictly ascending
            const float4 a = *(const float4*)&As[kk][ty * 4];
            const float4 b = *(const float4*)&Bs[kk][tx * 4];
            const float av[4] = {a.x, a.y, a.z, a.w};
            const float bv[4] = {b.x, b.y, b.z, b.w};
            #pragma unroll
            for (int i = 0; i < 4; ++i)
                #pragma unroll
                for (int j = 0; j < 4; ++j)
                    acc[i][j] = __fmaf_rn(av[i], bv[j], acc[i][j]);
        }
    }
    #pragma unroll
    for (int i = 0; i < 4; ++i)                    // fold last (64-wide) panel
        #pragma unroll
        for (int j = 0; j < 4; ++j)
            tot[i][j] = __fadd_rn(tot[i][j], acc[i][j]);

    float bj[4];
    #pragma unroll
    for (int j = 0; j < 4; ++j) bj[j] = bias[n0 + tx * 4 + j];

    #pragma unroll
    for (int i = 0; i < 4; ++i) {
        float4 v;
        float* op = out + (size_t)(m0 + ty * 4 + i) * NDIM + n0 + tx * 4;
        v.x = __fadd_rn(tot[i][0], bj[0]);
        v.y = __fadd_rn(tot[i][1], bj[1]);
        v.z = __fadd_rn(tot[i][2], bj[2]);
        v.w = __fadd_rn(tot[i][3], bj[3]);
        *(float4*)op = v;
    }
}

// ===========================================================================
// f32 scan, T=512, one thread per (b,d). 3-stage software pipeline:
//   raw[u]  : inputs for step t+4   (loaded 8 steps ahead)
//   xfm[u]  : transforms for step t (computed 4 steps ahead, fills stalls)
//   serial  : recurrence (the only true dependent chain)
// __launch_bounds__(64,1): only 1 wave/CU exists — unlock the VGPR budget so
// the compiler can keep the pipeline in registers (r7 got squeezed to 32).
// Inputs alias d_out and are overwritten in place by the same thread.
// ===========================================================================
__global__ __launch_bounds__(64, 1) void scan_kernel(
    float* __restrict__ log_h, float* __restrict__ sign_h, float* __restrict__ h_lin,
    const float* __restrict__ log_r_h, const float* __restrict__ sign_r_h)
{
    const int idx = blockIdx.x * 64 + threadIdx.x;
    const int d = idx & 1023;
    const float lrh = log_r_h[d];
    const float srh = sign_r_h[d];

    log_h[idx] = -40.0f;
    sign_h[idx] = 1.0f;

    float lhp = -40.0f;
    float shp = 1.0f;

    float ra[4], rl[4], rd[4];                       // raw inputs
    float xa[4], xl[4], xs[4], xd[4], xm[4];         // transformed

    // Prologue: raw for steps 0..3, transform them, then raw for steps 4..7.
    #pragma unroll
    for (int u = 0; u < 4; ++u) {
        ra[u] = h_lin[(size_t)u * BD + idx];
        rl[u] = log_h[(size_t)(u + 1) * BD + idx];
        rd[u] = sign_h[(size_t)(u + 1) * BD + idx];
    }
    #pragma unroll
    for (int u = 0; u < 4; ++u) {
        xform(ra[u], rl[u], rd[u], xa[u], xl[u], xs[u], xd[u], xm[u]);
        ra[u] = h_lin[(size_t)(u + 4) * BD + idx];
        rl[u] = log_h[(size_t)(u + 5) * BD + idx];
        rd[u] = sign_h[(size_t)(u + 5) * BD + idx];
    }

    for (int t4 = 0; t4 < TT; t4 += 4) {
        #pragma unroll
        for (int u = 0; u < 4; ++u) {
            const int t = t4 + u;
            // 1. serial recurrence for step t (consumes ready registers)
            serial_step(xa[u], xl[u], xs[u], xd[u], xm[u], lrh, srh, lhp, shp,
                        &log_h[(size_t)(t + 1) * BD + idx],
                        &sign_h[(size_t)(t + 1) * BD + idx],
                        &h_lin[(size_t)t * BD + idx]);
            // 2. transform for step t+4 (independent — fills serial stalls)
            if (t + 4 < TT)
                xform(ra[u], rl[u], rd[u], xa[u], xl[u], xs[u], xd[u], xm[u]);
            // 3. prefetch raw inputs for step t+8
            if (t + 8 < TT) {
                ra[u] = h_lin[(size_t)(t + 8) * BD + idx];
                rl[u] = log_h[(size_t)(t + 9) * BD + idx];
                rd[u] = sign_h[(size_t)(t + 9) * BD + idx];
            }
        }
    }
}

// ===========================================================================
extern "C" void kernel_launch(void* const* d_in, const int* in_sizes, int n_in,
                              void* d_out, int out_size, void* d_ws, size_t ws_size,
                              hipStream_t stream) {
    const float* x        = (const float*)d_in[0];
    const float* W_x      = (const float*)d_in[1];
    const float* W_alpha  = (const float*)d_in[2];
    const float* W_delta  = (const float*)d_in[3];
    const float* b        = (const float*)d_in[4];
    const float* b_alpha  = (const float*)d_in[5];
    const float* b_delta  = (const float*)d_in[6];
    const float* log_r_h  = (const float*)d_in[7];
    const float* sign_r_h = (const float*)d_in[8];

    float* out    = (float*)d_out;
    float* log_h  = out;                            // [513, BD]
    float* sign_h = out + (size_t)513 * BD;         // [513, BD]
    float* h_lin  = out + (size_t)2 * 513 * BD;     // [512, BD]

    dim3 ggrid(GEMM_M / 64, NDIM / 64, 3);
    gemm_blas<<<ggrid, dim3(256), 0, stream>>>(
        x, W_alpha, W_x, W_delta, b_alpha, b, b_delta,
        h_lin, log_h + BD, sign_h + BD);

    scan_kernel<<<dim3(BD / 64), dim3(64), 0, stream>>>(
        log_h, sign_h, h_lin, log_r_h, sign_r_h);
}

// Round 9
// 1614.744 us; speedup vs baseline: 1.3768x; 1.1908x over previous
//
#include <hip/hip_runtime.h>
#include <math.h>

#define BD 16384            // B*D
#define TT 512
#define KDIM 1024
#define NDIM 1024
#define GEMM_M 8192
#define PANEL_Q 320         // OpenBLAS SGEMM_DEFAULT_Q (SKYLAKEX/COOPERLAKE AVX512 path)
#define LOGE2F 0.69314718246459960938f

// ===========================================================================
// Scan transcendentals: ROCm native f32 libm — FROZEN (r7/r8 passed).
// Compound arithmetic uses __fadd_rn/__fmul_rn/__fsub_rn to forbid FMA
// contraction. Values are op-for-op identical to r7/r8; np_softplus is now
// BRANCHLESS but per-lane bit-identical (same expf/log1pf args in all cases;
// v<0 path 0+l1 == l1 exactly; v==0 handled by select).
// ===========================================================================
__device__ __forceinline__ float np_expf(float x)   { return expf(x); }
__device__ __forceinline__ float np_logf(float x)   { return logf(x); }
__device__ __forceinline__ float np_log1pf(float x) { return log1pf(x); }

__device__ __forceinline__ float np_softplus(float v) {
    const float e  = np_expf(-fabsf(v));
    const float l1 = np_log1pf(e);
    const float r  = __fadd_rn(fmaxf(v, 0.0f), l1);
    return (v == 0.0f) ? LOGE2F : r;      // npy_logaddexpf x==y special case
}

__device__ __forceinline__ void np_sla(float la, float sa, float lb, float sb,
                                       float& lo, float& so) {
    bool az = la <= -39.0f;                  // LOG_ZERO + 1
    bool bz = lb <= -39.0f;
    float mx = fmaxf(la, lb);
    float mn = fminf(la, lb);
    float diff = __fsub_rn(mn, mx);
    bool amax = la >= lb;
    float smax = amax ? sa : sb;
    float smin = amax ? sb : sa;
    bool same = __fmul_rn(smax, smin) > 0.0f;
    float ed = np_expf(diff);
    float ls  = __fadd_rn(mx, np_log1pf(ed));
    float lop = __fadd_rn(mx, np_log1pf(-fminf(ed, 0.9999f)));
    float l = same ? ls : lop;
    float s = smax;
    l = az ? lb : l;  s = az ? sb : s;
    bool bo = bz && !az;
    l = bo ? la : l;  s = bo ? sa : s;
    lo = l; so = s;
}

// ===========================================================================
// OpenBLAS-sgemm-exact NT-GEMM — FROZEN (r7/r8 passed): single-accumulator
// FMA chain, k ascending, Q=320 panels {320,320,320,64}, left-assoc fold,
// bias as separate f32 add. Tile 64x64, BK=16, 256 threads, 4x4 per thread.
// ===========================================================================
__global__ __launch_bounds__(256) void gemm_blas(
    const float* __restrict__ x,
    const float* __restrict__ Wa, const float* __restrict__ Wx, const float* __restrict__ Wd,
    const float* __restrict__ ba, const float* __restrict__ bx, const float* __restrict__ bd,
    float* __restrict__ out_a, float* __restrict__ out_x, float* __restrict__ out_d)
{
    const int z = blockIdx.z;
    const float* W    = (z == 0) ? Wa : (z == 1) ? Wx : Wd;
    const float* bias = (z == 0) ? ba : (z == 1) ? bx : bd;
    float* out        = (z == 0) ? out_a : (z == 1) ? out_x : out_d;

    const int m0 = blockIdx.x * 64;
    const int n0 = blockIdx.y * 64;

    __shared__ float As[16][68];   // [k in tile][m]
    __shared__ float Bs[16][68];   // [k in tile][n]

    const int tid = threadIdx.x;
    const int lr = tid >> 2;       // 0..63 staging row
    const int lc = tid & 3;        // float4 column
    const int ty = tid >> 4;       // 0..15 -> m = ty*4 + i
    const int tx = tid & 15;       // 0..15 -> n = tx*4 + j

    const float* Ap = x + (size_t)(m0 + lr) * KDIM + lc * 4;
    const float* Bp = W + (size_t)(n0 + lr) * KDIM + lc * 4;

    float4 fa = *(const float4*)Ap;
    float4 fb = *(const float4*)Bp;

    float tot[4][4];               // folded finished panels
    float acc[4][4];               // current panel FMA chain
    #pragma unroll
    for (int i = 0; i < 4; ++i)
        #pragma unroll
        for (int j = 0; j < 4; ++j) { tot[i][j] = 0.0f; acc[i][j] = 0.0f; }

    for (int kt = 0; kt < KDIM; kt += 16) {
        if (kt == PANEL_Q || kt == 2 * PANEL_Q || kt == 3 * PANEL_Q) {
            #pragma unroll
            for (int i = 0; i < 4; ++i)
                #pragma unroll
                for (int j = 0; j < 4; ++j) {
                    tot[i][j] = __fadd_rn(tot[i][j], acc[i][j]);  // C += panel
                    acc[i][j] = 0.0f;
                }
        }
        __syncthreads();
        {
            const float* pa = (const float*)&fa;
            const float* pb = (const float*)&fb;
            #pragma unroll
            for (int c = 0; c < 4; ++c) {
                As[lc * 4 + c][lr] = pa[c];
                Bs[lc * 4 + c][lr] = pb[c];
            }
        }
        __syncthreads();
        if (kt + 16 < KDIM) {
            fa = *(const float4*)(Ap + kt + 16);
            fb = *(const float4*)(Bp + kt + 16);
        }
        #pragma unroll
        for (int kk = 0; kk < 16; ++kk) {          // k strictly ascending
            const float4 a = *(const float4*)&As[kk][ty * 4];
            const float4 b = *(const float4*)&Bs[kk][tx * 4];
            const float av[4] = {a.x, a.y, a.z, a.w};
            const float bv[4] = {b.x, b.y, b.z, b.w};
            #pragma unroll
            for (int i = 0; i < 4; ++i)
                #pragma unroll
                for (int j = 0; j < 4; ++j)
                    acc[i][j] = __fmaf_rn(av[i], bv[j], acc[i][j]);
        }
    }
    #pragma unroll
    for (int i = 0; i < 4; ++i)                    // fold last (64-wide) panel
        #pragma unroll
        for (int j = 0; j < 4; ++j)
            tot[i][j] = __fadd_rn(tot[i][j], acc[i][j]);

    float bj[4];
    #pragma unroll
    for (int j = 0; j < 4; ++j) bj[j] = bias[n0 + tx * 4 + j];

    #pragma unroll
    for (int i = 0; i < 4; ++i) {
        float4 v;
        float* op = out + (size_t)(m0 + ty * 4 + i) * NDIM + n0 + tx * 4;
        v.x = __fadd_rn(tot[i][0], bj[0]);
        v.y = __fadd_rn(tot[i][1], bj[1]);
        v.z = __fadd_rn(tot[i][2], bj[2]);
        v.w = __fadd_rn(tot[i][3], bj[3]);
        *(float4*)op = v;
    }
}

// ===========================================================================
// f32 scan, T=512 as 128 groups of 4. Double-buffered group prefetch (A/B),
// no conditionals in the steady-state body (tail prefetch clamps to group
// 127 — values discarded, reads own column only). sched_barrier(0) pins each
// 12-load batch so it cannot sink into the next serial phase. Branchless
// helpers keep each half-iteration a single basic block so the independent
// xform work interleaves into the serial chain's latency stalls.
// ===========================================================================
__global__ __launch_bounds__(64, 1) void scan_kernel(
    float* __restrict__ log_h, float* __restrict__ sign_h, float* __restrict__ h_lin,
    const float* __restrict__ log_r_h, const float* __restrict__ sign_r_h)
{
    const int idx = blockIdx.x * 64 + threadIdx.x;
    const int d = idx & 1023;
    const float lrh = log_r_h[d];
    const float srh = sign_r_h[d];

    log_h[idx] = -40.0f;
    sign_h[idx] = 1.0f;

    float lhp = -40.0f;
    float shp = 1.0f;

    float Aa[4], Al[4], Ad[4];     // raw buffer A
    float Ba[4], Bl[4], Bd[4];     // raw buffer B
    float Xa[4], Xli[4], Xsi[4], Xld[4], Xlm[4];   // transformed (current group)

#define LOADG(GG, Ra, Rl, Rd) do {                                   \
    const int _b = (GG) * 4;                                         \
    _Pragma("unroll")                                                \
    for (int u = 0; u < 4; ++u) {                                    \
        Ra[u] = h_lin[(_b + u) * BD + idx];                          \
        Rl[u] = log_h[(_b + u + 1) * BD + idx];                      \
        Rd[u] = sign_h[(_b + u + 1) * BD + idx];                     \
    } } while (0)

// xform: bit-identical to r8's (which passed). alpha=1+softplus(araw);
// log_in/sign_in from lin; log_d/log_1md share e,l1 per numpy's branches.
#define XFORM(Ra, Rl, Rd) do {                                       \
    _Pragma("unroll")                                                \
    for (int u = 0; u < 4; ++u) {                                    \
        Xa[u] = __fadd_rn(1.0f, np_softplus(Ra[u]));                 \
        const float ax = fabsf(Rl[u]);                               \
        Xli[u] = (ax > 1e-10f) ? np_logf(fmaxf(ax, 1e-10f)) : -40.0f;\
        Xsi[u] = (Rl[u] < 0.0f) ? -1.0f : 1.0f;                      \
        const float dr = Rd[u];                                      \
        const float e  = np_expf(-fabsf(dr));                        \
        const float l1 = np_log1pf(e);                               \
        const float big = -__fadd_rn(fabsf(dr), l1);                 \
        const float sml = -l1;                                       \
        const float ld0 = (dr > 0.0f) ? sml : big;                   \
        const float lm0 = (dr > 0.0f) ? big : sml;                   \
        Xld[u] = (dr == 0.0f) ? -LOGE2F : ld0;                       \
        Xlm[u] = (dr == 0.0f) ? -LOGE2F : lm0;                       \
    } } while (0)

#define SERIAL4(GG) do {                                             \
    _Pragma("unroll")                                                \
    for (int u = 0; u < 4; ++u) {                                    \
        const int t = (GG) * 4 + u;                                  \
        const float log_rh  = __fadd_rn(lrh, lhp);                   \
        const float sign_rh = __fmul_rn(srh, shp);                   \
        float lv, sv;                                                \
        np_sla(log_rh, sign_rh, Xli[u], Xsi[u], lv, sv);             \
        const float tt = __fmul_rn(Xa[u], lv);                       \
        const float log_cand = -np_softplus(-tt);                    \
        float lhn, shn;                                              \
        np_sla(__fadd_rn(Xlm[u], lhp), shp,                          \
               __fadd_rn(Xld[u], log_cand), sv, lhn, shn);           \
        const float res = __fmul_rn(shn, np_expf(fminf(lhn, 20.0f)));\
        const float h = (lhn > -39.0f) ? res : 0.0f;                 \
        log_h[(t + 1) * BD + idx] = lhn;                             \
        sign_h[(t + 1) * BD + idx] = shn;                            \
        h_lin[t * BD + idx] = h;                                     \
        lhp = lhn; shp = shn;                                        \
    } } while (0)

    // Prologue: invariant at loop top — X=xform(g), B=raw(g+1), A=inflight(g+2)
    LOADG(0, Aa, Al, Ad);
    LOADG(1, Ba, Bl, Bd);
    XFORM(Aa, Al, Ad);                 // X = xform(group 0)
    LOADG(2, Aa, Al, Ad);              // A <- group 2 (in flight)
    __builtin_amdgcn_sched_barrier(0);

    for (int g = 0; g < 128; g += 2) {
        SERIAL4(g);                    // consume X = xform(g)
        XFORM(Ba, Bl, Bd);             // X = xform(g+1)
        { const int gg = (g + 3 < 128) ? g + 3 : 127;
          LOADG(gg, Ba, Bl, Bd); }     // B <- raw(g+3) in flight
        __builtin_amdgcn_sched_barrier(0);

        SERIAL4(g + 1);                // consume X = xform(g+1)
        XFORM(Aa, Al, Ad);             // X = xform(g+2)  (A arrived)
        { const int gg = (g + 4 < 128) ? g + 4 : 127;
          LOADG(gg, Aa, Al, Ad); }     // A <- raw(g+4) in flight
        __builtin_amdgcn_sched_barrier(0);
    }
#undef LOADG
#undef XFORM
#undef SERIAL4
}

// ===========================================================================
extern "C" void kernel_launch(void* const* d_in, const int* in_sizes, int n_in,
                              void* d_out, int out_size, void* d_ws, size_t ws_size,
                              hipStream_t stream) {
    const float* x        = (const float*)d_in[0];
    const float* W_x      = (const float*)d_in[1];
    const float* W_alpha  = (const float*)d_in[2];
    const float* W_delta  = (const float*)d_in[3];
    const float* b        = (const float*)d_in[4];
    const float* b_alpha  = (const float*)d_in[5];
    const float* b_delta  = (const float*)d_in[6];
    const float* log_r_h  = (const float*)d_in[7];
    const float* sign_r_h = (const float*)d_in[8];

    float* out    = (float*)d_out;
    float* log_h  = out;                            // [513, BD]
    float* sign_h = out + (size_t)513 * BD;         // [513, BD]
    float* h_lin  = out + (size_t)2 * 513 * BD;     // [512, BD]

    dim3 ggrid(GEMM_M / 64, NDIM / 64, 3);
    gemm_blas<<<ggrid, dim3(256), 0, stream>>>(
        x, W_alpha, W_x, W_delta, b_alpha, b, b_delta,
        h_lin, log_h + BD, sign_h + BD);

    scan_kernel<<<dim3(BD / 64), dim3(64), 0, stream>>>(
        log_h, sign_h, h_lin, log_r_h, sign_r_h);
}